// Round 6
// baseline (375.200 us; speedup 1.0000x reference)
//
#include <hip/hip_runtime.h>

#define N 16384
#define IN_F 128
#define OUT_F 32
#define ROWS 16          // adj rows per WG (one 16-row M-tile)
#define KH (N / 2)       // k per wave (two k-halves per WG)

typedef __attribute__((ext_vector_type(8))) short short8v;
typedef __attribute__((ext_vector_type(4))) float float4v;

// fp32 -> bf16 bits, round-to-nearest-even (finite inputs only)
__device__ __forceinline__ unsigned short f2bf(float x) {
    unsigned int u = __float_as_uint(x);
    u += 0x7FFFu + ((u >> 16) & 1u);
    return (unsigned short)(u >> 16);
}

// Kernel A: supB[j][i] = bf16( sum_k input[i][k] * weight[k][j] )  (transposed support, bf16)
__global__ __launch_bounds__(256) void gcn_support(const float* __restrict__ inp,
                                                   const float* __restrict__ w,
                                                   unsigned short* __restrict__ supB) {
    __shared__ float wl[IN_F * OUT_F];  // 16 KB
    int tid = threadIdx.x;
#pragma unroll
    for (int u = 0; u < 4; ++u) {
        int idx = (u * 256 + tid) * 4;
        *(float4*)&wl[idx] = *(const float4*)&w[idx];
    }
    __syncthreads();

    int gid = blockIdx.x * 256 + tid;
    int i  = gid >> 2;   // row 0..16383
    int ks = gid & 3;    // k quarter

    float acc[OUT_F];
#pragma unroll
    for (int j = 0; j < OUT_F; ++j) acc[j] = 0.f;

    const float* ip = inp + (size_t)i * IN_F + ks * 32;
#pragma unroll
    for (int kb = 0; kb < 8; ++kb) {
        float4 a4 = *(const float4*)(ip + kb * 4);
        float av[4] = {a4.x, a4.y, a4.z, a4.w};
#pragma unroll
        for (int kk = 0; kk < 4; ++kk) {
            int k = ks * 32 + kb * 4 + kk;
            const float* wr = &wl[k * OUT_F];
#pragma unroll
            for (int j4 = 0; j4 < 8; ++j4) {
                float4 w4 = *(const float4*)(wr + j4 * 4);
                acc[j4 * 4 + 0] = fmaf(av[kk], w4.x, acc[j4 * 4 + 0]);
                acc[j4 * 4 + 1] = fmaf(av[kk], w4.y, acc[j4 * 4 + 1]);
                acc[j4 * 4 + 2] = fmaf(av[kk], w4.z, acc[j4 * 4 + 2]);
                acc[j4 * 4 + 3] = fmaf(av[kk], w4.w, acc[j4 * 4 + 3]);
            }
        }
    }
#pragma unroll
    for (int j = 0; j < OUT_F; ++j) {
        acc[j] += __shfl_xor(acc[j], 1);
        acc[j] += __shfl_xor(acc[j], 2);
    }
#pragma unroll
    for (int jj = 0; jj < 8; ++jj) {
        int j = ks * 8 + jj;
        supB[(size_t)j * N + i] = f2bf(acc[j]);
    }
}

// Kernel B: out = relu(adj @ sup) via bf16 MFMA, barrier-free streaming.
// WG = 16 rows; 4 waves = nt(2 col-tiles) x kh(2 k-halves). No LDS staging:
// A-fragment loads (16 rows x 128B aligned segments) are perfectly
// line-efficient straight from global; B (supB) is L2-resident.
// k-halves combine via 2KB LDS at the end; relu+store final (no atomics).
__global__ __launch_bounds__(256, 4) void gcn_aggregate(const float* __restrict__ adj,
                                                        const unsigned short* __restrict__ supB,
                                                        float* __restrict__ out) {
    __shared__ float sRed[2][16 * 16];  // [nt][row][col] partial from kh=1

    int rb   = blockIdx.x;       // 1024 row tiles
    int tid  = threadIdx.x;
    int wv   = tid >> 6;
    int lane = tid & 63;
    int nt = wv & 1;             // col tile 0..1
    int kh = wv >> 1;            // k half 0..1
    int lr = lane & 15;          // A row / B col within tile
    int kg = lane >> 4;          // k-group 0..3 (8 k each)

    int rowblk = rb * ROWS;
    size_t kbase = (size_t)kh * KH + kg * 8;

    const float* ap = adj + (size_t)(rowblk + lr) * N + kbase;
    const unsigned short* bp = supB + (size_t)(nt * 16 + lr) * N + kbase;

    float4v acc = {0.f, 0.f, 0.f, 0.f};

#pragma unroll 4
    for (int it = 0; it < KH / 32; ++it) {
        const float* a = ap + (size_t)it * 32;
        float4 a0 = *(const float4*)(a);
        float4 a1 = *(const float4*)(a + 4);
        short8v b = *(const short8v*)(bp + (size_t)it * 32);
        short8v af;
        af[0] = (short)f2bf(a0.x); af[1] = (short)f2bf(a0.y);
        af[2] = (short)f2bf(a0.z); af[3] = (short)f2bf(a0.w);
        af[4] = (short)f2bf(a1.x); af[5] = (short)f2bf(a1.y);
        af[6] = (short)f2bf(a1.z); af[7] = (short)f2bf(a1.w);
        acc = __builtin_amdgcn_mfma_f32_16x16x32_bf16(af, b, acc, 0, 0, 0);
    }

    // C/D layout: col = lane&15, row = (lane>>4)*4 + reg  (m89; validated by R5 pass)
    if (kh == 1) {
#pragma unroll
        for (int r = 0; r < 4; ++r)
            sRed[nt][(kg * 4 + r) * 16 + lr] = acc[r];
    }
    __syncthreads();
    if (kh == 0) {
#pragma unroll
        for (int r = 0; r < 4; ++r) {
            float s = acc[r] + sRed[nt][(kg * 4 + r) * 16 + lr];
            out[(size_t)(rowblk + kg * 4 + r) * OUT_F + nt * 16 + lr] = fmaxf(s, 0.f);
        }
    }
}

extern "C" void kernel_launch(void* const* d_in, const int* in_sizes, int n_in,
                              void* d_out, int out_size, void* d_ws, size_t ws_size,
                              hipStream_t stream) {
    (void)in_sizes; (void)n_in; (void)out_size; (void)ws_size;
    const float* inp = (const float*)d_in[0];   // [16384,128]
    const float* adj = (const float*)d_in[1];   // [16384,16384]
    const float* wgt = (const float*)d_in[2];   // [128,32]
    float* out = (float*)d_out;                 // [16384,32]
    unsigned short* supB = (unsigned short*)d_ws;  // [32][16384] bf16 = 1 MB

    gcn_support<<<(N * 4) / 256, 256, 0, stream>>>(inp, wgt, supB);
    gcn_aggregate<<<N / ROWS, 256, 0, stream>>>(adj, supB, out);
}

// Round 7
// 307.681 us; speedup vs baseline: 1.2194x; 1.2194x over previous
//
#include <hip/hip_runtime.h>

#define N 16384
#define IN_F 128
#define OUT_F 32
#define ROWS 16             // adj rows per WG
#define KC 1024             // k per chunk -> 4 KB contiguous per row per chunk
#define CHUNKS (N / KC)     // 16

typedef __attribute__((ext_vector_type(8))) short short8v;
typedef __attribute__((ext_vector_type(4))) float float4v;

#define GLOAD_LDS16(g, l) \
    __builtin_amdgcn_global_load_lds((const __attribute__((address_space(1))) void*)(g), \
                                     (__attribute__((address_space(3))) void*)(l), 16, 0, 0)

// fp32 -> bf16 bits, round-to-nearest-even (finite inputs only)
__device__ __forceinline__ unsigned short f2bf(float x) {
    unsigned int u = __float_as_uint(x);
    u += 0x7FFFu + ((u >> 16) & 1u);
    return (unsigned short)(u >> 16);
}

// Kernel A: supB[j][i] = bf16( sum_k input[i][k] * weight[k][j] )  (transposed support, bf16)
__global__ __launch_bounds__(256) void gcn_support(const float* __restrict__ inp,
                                                   const float* __restrict__ w,
                                                   unsigned short* __restrict__ supB) {
    __shared__ float wl[IN_F * OUT_F];  // 16 KB
    int tid = threadIdx.x;
#pragma unroll
    for (int u = 0; u < 4; ++u) {
        int idx = (u * 256 + tid) * 4;
        *(float4*)&wl[idx] = *(const float4*)&w[idx];
    }
    __syncthreads();

    int gid = blockIdx.x * 256 + tid;
    int i  = gid >> 2;   // row 0..16383
    int ks = gid & 3;    // k quarter

    float acc[OUT_F];
#pragma unroll
    for (int j = 0; j < OUT_F; ++j) acc[j] = 0.f;

    const float* ip = inp + (size_t)i * IN_F + ks * 32;
#pragma unroll
    for (int kb = 0; kb < 8; ++kb) {
        float4 a4 = *(const float4*)(ip + kb * 4);
        float av[4] = {a4.x, a4.y, a4.z, a4.w};
#pragma unroll
        for (int kk = 0; kk < 4; ++kk) {
            int k = ks * 32 + kb * 4 + kk;
            const float* wr = &wl[k * OUT_F];
#pragma unroll
            for (int j4 = 0; j4 < 8; ++j4) {
                float4 w4 = *(const float4*)(wr + j4 * 4);
                acc[j4 * 4 + 0] = fmaf(av[kk], w4.x, acc[j4 * 4 + 0]);
                acc[j4 * 4 + 1] = fmaf(av[kk], w4.y, acc[j4 * 4 + 1]);
                acc[j4 * 4 + 2] = fmaf(av[kk], w4.z, acc[j4 * 4 + 2]);
                acc[j4 * 4 + 3] = fmaf(av[kk], w4.w, acc[j4 * 4 + 3]);
            }
        }
    }
#pragma unroll
    for (int j = 0; j < OUT_F; ++j) {
        acc[j] += __shfl_xor(acc[j], 1);
        acc[j] += __shfl_xor(acc[j], 2);
    }
#pragma unroll
    for (int jj = 0; jj < 8; ++jj) {
        int j = ks * 8 + jj;
        supB[(size_t)j * N + i] = f2bf(acc[j]);
    }
}

// Kernel B: out = relu(adj @ sup) via bf16 MFMA.
// WG = 16 rows x full k; 4 waves = nt(2 col-tiles) x kh(2 k-halves of chunk).
// adj DMA-staged in 64-KB chunks (4 KB contiguous per row -> DRAM-page
// friendly), double-buffered; chunk c+1 stays in flight across compute of c
// (the vmcnt(0) at iter end waits on loads issued one HBM-paced iter ago).
// B-fragments prefetched to VGPR BEFORE the stage so in-order vmcnt never
// forces a DMA drain. kh halves combine via LDS; direct relu store.
__global__ __launch_bounds__(256, 1) void gcn_aggregate(const float* __restrict__ adj,
                                                        const unsigned short* __restrict__ supB,
                                                        float* __restrict__ out) {
    __shared__ float sA[2][ROWS * KC];  // 128 KB, XOR-swizzled [row][k]
    __shared__ float sRed[2][16 * 16];  // kh=1 partials, 2 KB

    int rb   = blockIdx.x;       // 1024 row tiles
    int tid  = threadIdx.x;
    int wv   = tid >> 6;
    int lane = tid & 63;
    int nt = wv & 1;             // col tile 0..1
    int kh = wv >> 1;            // k half of chunk, 0..1
    int lr = lane & 15;          // A row / B col within tile
    int kg = lane >> 4;          // k-group 0..3 (8 k each)

    int rowblk = rb * ROWS;

    const unsigned short* bp = supB + (size_t)(nt * 16 + lr) * N + kg * 8;

    float4v acc = {0.f, 0.f, 0.f, 0.f};

    // Stage chunk c (16 rows x 4 KB) -> sA[buf], 16 x dwordx4 per thread.
    // Slot f = u*256+tid: row = f>>8, blk = f&255 (16B blocks). LDS dest is
    // linear (wave base + lane*16B); XOR swizzle (blk ^ (row&7)) applied on
    // the GLOBAL side; reads apply the same XOR (involution, rule #21).
    // Each wave-instr = 64 consecutive blks of one row = 1 KB contiguous.
    auto stage = [&](int buf, int c) {
#pragma unroll
        for (int u = 0; u < 16; ++u) {
            int f    = u * 256 + tid;
            int row  = f >> 8;
            int blk  = f & 255;
            int gblk = blk ^ (row & 7);
            const float* gp = adj + (size_t)(rowblk + row) * N + (size_t)c * KC + gblk * 4;
            float* lp = &sA[buf][(u * 256 + wv * 64) * 4];  // wave-uniform base
            GLOAD_LDS16(gp, lp);
        }
    };

    stage(0, 0);
    asm volatile("s_waitcnt vmcnt(0)" ::: "memory");
    __builtin_amdgcn_s_barrier();

    int sw = lr & 7;  // read-side swizzle key (row = lr)

    for (int c = 0; c < CHUNKS; ++c) {
        int cur = c & 1;

        // B fragments for chunk c (L2-resident; issued BEFORE the DMA stage)
        short8v bq[16];
#pragma unroll
        for (int it = 0; it < 16; ++it)
            bq[it] = *(const short8v*)(bp + (size_t)c * KC + kh * 512 + it * 32);

        if (c + 1 < CHUNKS) stage(cur ^ 1, c + 1);  // in flight across compute

#pragma unroll
        for (int it = 0; it < 16; ++it) {
            int blk0 = kh * 128 + it * 8 + kg * 2;
            float4 a0 = *(const float4*)&sA[cur][(size_t)lr * KC + ((blk0 ^ sw) << 2)];
            float4 a1 = *(const float4*)&sA[cur][(size_t)lr * KC + (((blk0 + 1) ^ sw) << 2)];
            short8v af;
            af[0] = (short)f2bf(a0.x); af[1] = (short)f2bf(a0.y);
            af[2] = (short)f2bf(a0.z); af[3] = (short)f2bf(a0.w);
            af[4] = (short)f2bf(a1.x); af[5] = (short)f2bf(a1.y);
            af[6] = (short)f2bf(a1.z); af[7] = (short)f2bf(a1.w);
            acc = __builtin_amdgcn_mfma_f32_16x16x32_bf16(af, bq[it], acc, 0, 0, 0);
        }

        // Wait for chunk c+1 (issued one HBM-paced iteration ago) + publish.
        asm volatile("s_waitcnt vmcnt(0)" ::: "memory");
        __builtin_amdgcn_sched_barrier(0);
        __builtin_amdgcn_s_barrier();
        __builtin_amdgcn_sched_barrier(0);
    }

    // Combine kh halves. C/D layout: col = lane&15, row = (lane>>4)*4 + reg.
    if (kh == 1) {
#pragma unroll
        for (int r = 0; r < 4; ++r)
            sRed[nt][(kg * 4 + r) * 16 + lr] = acc[r];
    }
    __syncthreads();
    if (kh == 0) {
#pragma unroll
        for (int r = 0; r < 4; ++r) {
            float s = acc[r] + sRed[nt][(kg * 4 + r) * 16 + lr];
            out[(size_t)(rowblk + kg * 4 + r) * OUT_F + nt * 16 + lr] = fmaxf(s, 0.f);
        }
    }
}

extern "C" void kernel_launch(void* const* d_in, const int* in_sizes, int n_in,
                              void* d_out, int out_size, void* d_ws, size_t ws_size,
                              hipStream_t stream) {
    (void)in_sizes; (void)n_in; (void)out_size; (void)ws_size;
    const float* inp = (const float*)d_in[0];   // [16384,128]
    const float* adj = (const float*)d_in[1];   // [16384,16384]
    const float* wgt = (const float*)d_in[2];   // [128,32]
    float* out = (float*)d_out;                 // [16384,32]
    unsigned short* supB = (unsigned short*)d_ws;  // [32][16384] bf16 = 1 MB

    gcn_support<<<(N * 4) / 256, 256, 0, stream>>>(inp, wgt, supB);
    gcn_aggregate<<<N / ROWS, 256, 0, stream>>>(adj, supB, out);
}

// Round 8
// 216.926 us; speedup vs baseline: 1.7296x; 1.4184x over previous
//
#include <hip/hip_runtime.h>

#define N 16384
#define IN_F 128
#define OUT_F 32
#define ROWS 16             // adj rows per WG
#define KC 256              // k per chunk -> 1 KB contiguous per row per chunk
#define CHUNKS (N / KC)     // 64

typedef __attribute__((ext_vector_type(8))) short short8v;
typedef __attribute__((ext_vector_type(4))) float float4v;

#define GLOAD_LDS16(g, l) \
    __builtin_amdgcn_global_load_lds((const __attribute__((address_space(1))) void*)(g), \
                                     (__attribute__((address_space(3))) void*)(l), 16, 0, 0)

// fp32 -> bf16 bits, round-to-nearest-even (finite inputs only)
__device__ __forceinline__ unsigned short f2bf(float x) {
    unsigned int u = __float_as_uint(x);
    u += 0x7FFFu + ((u >> 16) & 1u);
    return (unsigned short)(u >> 16);
}

// Kernel A: supB[j][i] = bf16( sum_k input[i][k] * weight[k][j] )  (transposed support, bf16)
__global__ __launch_bounds__(256) void gcn_support(const float* __restrict__ inp,
                                                   const float* __restrict__ w,
                                                   unsigned short* __restrict__ supB) {
    __shared__ float wl[IN_F * OUT_F];  // 16 KB
    int tid = threadIdx.x;
#pragma unroll
    for (int u = 0; u < 4; ++u) {
        int idx = (u * 256 + tid) * 4;
        *(float4*)&wl[idx] = *(const float4*)&w[idx];
    }
    __syncthreads();

    int gid = blockIdx.x * 256 + tid;
    int i  = gid >> 2;   // row 0..16383
    int ks = gid & 3;    // k quarter

    float acc[OUT_F];
#pragma unroll
    for (int j = 0; j < OUT_F; ++j) acc[j] = 0.f;

    const float* ip = inp + (size_t)i * IN_F + ks * 32;
#pragma unroll
    for (int kb = 0; kb < 8; ++kb) {
        float4 a4 = *(const float4*)(ip + kb * 4);
        float av[4] = {a4.x, a4.y, a4.z, a4.w};
#pragma unroll
        for (int kk = 0; kk < 4; ++kk) {
            int k = ks * 32 + kb * 4 + kk;
            const float* wr = &wl[k * OUT_F];
#pragma unroll
            for (int j4 = 0; j4 < 8; ++j4) {
                float4 w4 = *(const float4*)(wr + j4 * 4);
                acc[j4 * 4 + 0] = fmaf(av[kk], w4.x, acc[j4 * 4 + 0]);
                acc[j4 * 4 + 1] = fmaf(av[kk], w4.y, acc[j4 * 4 + 1]);
                acc[j4 * 4 + 2] = fmaf(av[kk], w4.z, acc[j4 * 4 + 2]);
                acc[j4 * 4 + 3] = fmaf(av[kk], w4.w, acc[j4 * 4 + 3]);
            }
        }
    }
#pragma unroll
    for (int j = 0; j < OUT_F; ++j) {
        acc[j] += __shfl_xor(acc[j], 1);
        acc[j] += __shfl_xor(acc[j], 2);
    }
#pragma unroll
    for (int jj = 0; jj < 8; ++jj) {
        int j = ks * 8 + jj;
        supB[(size_t)j * N + i] = f2bf(acc[j]);
    }
}

// Kernel B: out = relu(adj @ sup) via bf16 MFMA, never-drain DMA pipeline.
// WG = 16 rows x full k; 4 waves = nt(2 col-tiles) x kh(2 k-halves of chunk).
// Per chunk: [bq B-frag loads] [stage(c+1) DMA] [s_waitcnt vmcnt(4)] -- the
// counted wait retires st(c)+bq but leaves st(c+1) in flight across both
// barriers and the compute (in-order vmcnt retire). Per-WG outstanding never
// reaches 0; 4 WG/CU keep >= 9.2 KB (BW x latency) in flight continuously.
// 1 KB contiguous per row per stage-instr for DRAM page locality.
__global__ __launch_bounds__(256, 4) void gcn_aggregate(const float* __restrict__ adj,
                                                        const unsigned short* __restrict__ supB,
                                                        float* __restrict__ out) {
    __shared__ float sA[2][ROWS * KC];  // 32 KB, XOR-swizzled [row][k]
    __shared__ float sRed[2][16 * 16];  // kh=1 partials, 2 KB

    int rb   = blockIdx.x;       // 1024 row tiles
    int tid  = threadIdx.x;
    int wv   = tid >> 6;
    int lane = tid & 63;
    int nt = wv & 1;             // col tile 0..1
    int kh = wv >> 1;            // k half of chunk, 0..1
    int lr = lane & 15;          // A row / B col within tile
    int kg = lane >> 4;          // k-group 0..3 (8 k each)

    int rowblk = rb * ROWS;

    const unsigned short* bp = supB + (size_t)(nt * 16 + lr) * N + kg * 8;

    float4v acc = {0.f, 0.f, 0.f, 0.f};

    // Stage chunk c (16 rows x 1 KB) -> sA[buf], 4 x dwordx4 per thread.
    // Slot f = u*256+tid: row = f>>6, blk = f&63 (16B blocks). One wave-instr
    // = 64 consecutive blocks of one row = 1 KB contiguous global. LDS dest
    // is linear (wave base + lane*16B); XOR swizzle (blk ^ (row&7)) applied
    // on the GLOBAL per-lane address; reads apply the same XOR (rule #21).
    auto stage = [&](int buf, int c) {
#pragma unroll
        for (int u = 0; u < 4; ++u) {
            int f    = u * 256 + tid;
            int row  = f >> 6;
            int blk  = f & 63;
            int gblk = blk ^ (row & 7);
            const float* gp = adj + (size_t)(rowblk + row) * N + (size_t)c * KC + gblk * 4;
            float* lp = &sA[buf][(u * 256 + wv * 64) * 4];  // wave-uniform base
            GLOAD_LDS16(gp, lp);
        }
    };

    stage(0, 0);   // st(0) in flight

    int sw = lr & 7;  // read-side swizzle key (row = lr)

    for (int c = 0; c < CHUNKS; ++c) {
        int cur = c & 1;

        // readers of buf[cur^1] (= compute of c-1) are done before st(c+1) overwrites it
        __builtin_amdgcn_s_barrier();

        // B fragments for chunk c (L2-resident). Issued BEFORE the stage so
        // the counted wait below can retire them without draining st(c+1).
        short8v bq[4];
#pragma unroll
        for (int it = 0; it < 4; ++it)
            bq[it] = *(const short8v*)(bp + (size_t)c * KC + kh * 128 + it * 32);
        __builtin_amdgcn_sched_barrier(0);

        if (c + 1 < CHUNKS) {
            stage(cur ^ 1, c + 1);
            // outstanding (oldest first): st(c)[4] bq[4] st(c+1)[4]
            asm volatile("s_waitcnt vmcnt(4)" ::: "memory");  // retire st(c)+bq, keep st(c+1) in flight
        } else {
            asm volatile("s_waitcnt vmcnt(0)" ::: "memory");
        }
        __builtin_amdgcn_sched_barrier(0);
        __builtin_amdgcn_s_barrier();        // chunk c visible to all waves
        __builtin_amdgcn_sched_barrier(0);

#pragma unroll
        for (int it = 0; it < 4; ++it) {
            int blk0 = kh * 32 + it * 8 + kg * 2;
            float4 a0 = *(const float4*)&sA[cur][(size_t)lr * KC + (size_t)((blk0 ^ sw) << 2)];
            float4 a1 = *(const float4*)&sA[cur][(size_t)lr * KC + (size_t)(((blk0 + 1) ^ sw) << 2)];
            short8v af;
            af[0] = (short)f2bf(a0.x); af[1] = (short)f2bf(a0.y);
            af[2] = (short)f2bf(a0.z); af[3] = (short)f2bf(a0.w);
            af[4] = (short)f2bf(a1.x); af[5] = (short)f2bf(a1.y);
            af[6] = (short)f2bf(a1.z); af[7] = (short)f2bf(a1.w);
            acc = __builtin_amdgcn_mfma_f32_16x16x32_bf16(af, bq[it], acc, 0, 0, 0);
        }
    }

    // Combine kh halves. C/D layout: col = lane&15, row = (lane>>4)*4 + reg.
    if (kh == 1) {
#pragma unroll
        for (int r = 0; r < 4; ++r)
            sRed[nt][(kg * 4 + r) * 16 + lr] = acc[r];
    }
    __syncthreads();
    if (kh == 0) {
#pragma unroll
        for (int r = 0; r < 4; ++r) {
            float s = acc[r] + sRed[nt][(kg * 4 + r) * 16 + lr];
            out[(size_t)(rowblk + kg * 4 + r) * OUT_F + nt * 16 + lr] = fmaxf(s, 0.f);
        }
    }
}

extern "C" void kernel_launch(void* const* d_in, const int* in_sizes, int n_in,
                              void* d_out, int out_size, void* d_ws, size_t ws_size,
                              hipStream_t stream) {
    (void)in_sizes; (void)n_in; (void)out_size; (void)ws_size;
    const float* inp = (const float*)d_in[0];   // [16384,128]
    const float* adj = (const float*)d_in[1];   // [16384,16384]
    const float* wgt = (const float*)d_in[2];   // [128,32]
    float* out = (float*)d_out;                 // [16384,32]
    unsigned short* supB = (unsigned short*)d_ws;  // [32][16384] bf16 = 1 MB

    gcn_support<<<(N * 4) / 256, 256, 0, stream>>>(inp, wgt, supB);
    gcn_aggregate<<<N / ROWS, 256, 0, stream>>>(adj, supB, out);
}